// Round 1
// baseline (1497.106 us; speedup 1.0000x reference)
//
#include <hip/hip_runtime.h>
#include <hip/hip_bf16.h>
#include <float.h>

// Problem constants (PQHotShared): U[16384,64], B[64,4096], codebook[2048,16]
static constexpr int KCB    = 2048;   // codebook entries
static constexpr int DSUB   = 16;    // subvector length
static constexpr int NSUB_U = 65536; // 16384*64/16
static constexpr int NSUB_B = 16384; // 64*4096/16
static constexpr int NSUB   = NSUB_U + NSUB_B; // 81920
static constexpr int NQ     = 4;     // codebook split for load balance
static constexpr int CPQ    = KCB / NQ; // 512

typedef __attribute__((ext_vector_type(8))) short s16x8;   // 8 x bf16 (4 VGPRs)
typedef __attribute__((ext_vector_type(4))) float f32x4;

// ---------------- ws layout (bytes) ----------------
// pbest : 327680 * 4 = 1310720          @ 0
// pidx  : 327680 * 4 = 1310720          @ 1310720
// cb2   : 2048 * 4   = 8192             @ 2621440
// Uqh   : 16384*64*2 = 2097152 (bf16)   @ 2629632
// BqTh  : 4096*64*2  = 524288  (bf16)   @ 4726784
// total ~5.25 MB
static constexpr size_t OFF_PBEST = 0;
static constexpr size_t OFF_PIDX  = 1310720;
static constexpr size_t OFF_CB2   = 2621440;
static constexpr size_t OFF_UQH   = 2629632;
static constexpr size_t OFF_BQTH  = 4726784;

// ||cb_c||^2 with numpy pairwise order for n=16:
//   r[j] = a[j] + a[j+8];  res = ((r0+r1)+(r2+r3)) + ((r4+r5)+(r6+r7))
// squares via fmaf(v,v,0) == round(v*v), and fmaf blocks ffp-contract fusing
// the square into the following add.
__global__ __launch_bounds__(256) void cb2_kernel(const float* __restrict__ cb,
                                                  float* __restrict__ cb2) {
    int c = blockIdx.x * 256 + threadIdx.x;   // grid covers exactly 2048
    const float* p = cb + (size_t)c * DSUB;
    float a[16];
#pragma unroll
    for (int j = 0; j < 16; j++) { float v = p[j]; a[j] = fmaf(v, v, 0.0f); }
    float r[8];
#pragma unroll
    for (int j = 0; j < 8; j++) r[j] = a[j] + a[j + 8];
    float res = ((r[0] + r[1]) + (r[2] + r[3])) + ((r[4] + r[5]) + (r[6] + r[7]));
    cb2[c] = res;
}

// One thread per (subvector, codebook-quarter). 327680 threads, 5120 waves
// over 1024 SIMDs -> balanced. Codebook/cb2 reads are wave-uniform (s_load).
// Sequential fmaf chain over k matches BLAS sgemm accumulation order;
// d2 = cb2 - 2*dot (2*dot exact, contraction-immune); strict '<' argmin.
__global__ __launch_bounds__(256) void pq_partial(
    const float* __restrict__ U, const float* __restrict__ B,
    const float* __restrict__ rsU, const float* __restrict__ rsB,
    const float* __restrict__ cb, const float* __restrict__ cb2,
    float* __restrict__ pbest, int* __restrict__ pidx)
{
    int t = blockIdx.x * 256 + threadIdx.x;  // < 327680 exactly
    int sub = t >> 2, q = t & 3;

    const float* wp;
    float rs;
    if (sub < NSUB_U) {                // U subvector: row o = sub/4
        wp = U + (size_t)sub * DSUB;
        rs = rsU[sub >> 2];
    } else {                           // B subvector: row o = s/256
        int s = sub - NSUB_U;
        wp = B + (size_t)s * DSUB;
        rs = rsB[s >> 8];
    }
    float g[16];
#pragma unroll
    for (int k = 0; k < 16; k++) g[k] = wp[k] / rs;   // IEEE div, matches np

    const int c0 = q * CPQ;
    const float* cbp = cb + (size_t)c0 * DSUB;
    const float* c2p = cb2 + c0;

    float best = FLT_MAX;
    int bi = 0;
    for (int c = 0; c < CPQ; c += 4) {   // 4 independent chains for ILP
        const float* p0 = cbp + (size_t)c * DSUB;
        float d0 = 0.f, d1 = 0.f, d2 = 0.f, d3 = 0.f;
#pragma unroll
        for (int k = 0; k < 16; k++) {
            d0 = fmaf(g[k], p0[k],      d0);
            d1 = fmaf(g[k], p0[16 + k], d1);
            d2 = fmaf(g[k], p0[32 + k], d2);
            d3 = fmaf(g[k], p0[48 + k], d3);
        }
        float e0 = c2p[c + 0] - 2.0f * d0;
        float e1 = c2p[c + 1] - 2.0f * d1;
        float e2 = c2p[c + 2] - 2.0f * d2;
        float e3 = c2p[c + 3] - 2.0f * d3;
        if (e0 < best) { best = e0; bi = c + 0; }
        if (e1 < best) { best = e1; bi = c + 1; }
        if (e2 < best) { best = e2; bi = c + 2; }
        if (e3 < best) { best = e3; bi = c + 3; }
    }
    pbest[t] = best;
    pidx[t]  = c0 + bi;
}

// Merge the 4 quarter-results (in order -> first-index tie semantics),
// dequantize, cast to bf16. Uq stored [16384][64] row-major; Bq stored
// transposed as BqT [4096 cols][64 k] for MFMA B-fragment loads.
__global__ __launch_bounds__(256) void pq_combine(
    const float* __restrict__ cb,
    const float* __restrict__ rsU, const float* __restrict__ rsB,
    const float* __restrict__ pbest, const int* __restrict__ pidx,
    __hip_bfloat16* __restrict__ Uqh, __hip_bfloat16* __restrict__ BqTh)
{
    int sub = blockIdx.x * 256 + threadIdx.x;   // < 81920 exactly
    float4 b4 = ((const float4*)pbest)[sub];
    int4   i4 = ((const int4*)pidx)[sub];
    float best = b4.x; int bi = i4.x;
    if (b4.y < best) { best = b4.y; bi = i4.y; }
    if (b4.z < best) { best = b4.z; bi = i4.z; }
    if (b4.w < best) { best = b4.w; bi = i4.w; }

    const float* cp = cb + (size_t)bi * DSUB;
    if (sub < NSUB_U) {
        float rs = rsU[sub >> 2];
        union { __hip_bfloat16 h[16]; uint4 u4[2]; } u;
#pragma unroll
        for (int j = 0; j < 16; j++) u.h[j] = __float2bfloat16(cp[j] * rs);
        uint4* dst = (uint4*)(Uqh + (size_t)sub * DSUB);
        dst[0] = u.u4[0];
        dst[1] = u.u4[1];
    } else {
        int s = sub - NSUB_U;
        int kk = s >> 8;                 // B row (k index), 0..63
        int dbase = (s & 255) * DSUB;    // output column base
        float rs = rsB[kk];
#pragma unroll
        for (int j = 0; j < 16; j++)
            BqTh[(size_t)(dbase + j) * 64 + kk] = __float2bfloat16(cp[j] * rs);
    }
}

// C[16384,4096] = Uq @ Bq via mfma_f32_16x16x32_bf16, K=64 (2 mfma per tile).
// One wave computes a 16-row x 64-col strip (4 n-tiles). Operands straight
// from L2-resident bf16 tensors (A 2MB, BT 0.5MB). HBM-write-bound.
// Layouts (verified, learn_hip m89/m120): A-frag lane: A[m=l&15][k=quad*8+j];
// B-frag lane: B[k=quad*8+j][n=l&15] -> contiguous 16B from BT[n][k];
// C/D: col=l&15, row=quad*4+reg.
__global__ __launch_bounds__(256) void mm_mfma(
    const __hip_bfloat16* __restrict__ A,   // [16384][64]
    const __hip_bfloat16* __restrict__ BT,  // [4096][64]
    float* __restrict__ C)
{
    int wave = threadIdx.x >> 6;
    int lane = threadIdx.x & 63;
    int rb  = ((blockIdx.y << 2) | wave) << 4;   // row base, 16 rows
    int cb0 = blockIdx.x << 6;                   // col base, 64 cols
    int mrow = lane & 15;
    int quad = lane >> 4;
    int kidx = quad * 8;

    const s16x8* ap = (const s16x8*)(A + (size_t)(rb + mrow) * 64 + kidx);
    s16x8 a0 = ap[0];     // k in [kidx, kidx+8)
    s16x8 a1 = ap[4];     // k in [32+kidx, 32+kidx+8)

    f32x4 acc[4] = {};
#pragma unroll
    for (int nt = 0; nt < 4; nt++) {
        const s16x8* bp =
            (const s16x8*)(BT + (size_t)(cb0 + nt * 16 + mrow) * 64 + kidx);
        s16x8 b0 = bp[0];
        s16x8 b1 = bp[4];
        acc[nt] = __builtin_amdgcn_mfma_f32_16x16x32_bf16(a0, b0, acc[nt], 0, 0, 0);
        acc[nt] = __builtin_amdgcn_mfma_f32_16x16x32_bf16(a1, b1, acc[nt], 0, 0, 0);
    }

#pragma unroll
    for (int nt = 0; nt < 4; nt++) {
#pragma unroll
        for (int i = 0; i < 4; i++) {
            C[(size_t)(rb + quad * 4 + i) * 4096 + (cb0 + nt * 16 + mrow)] =
                acc[nt][i];
        }
    }
}

extern "C" void kernel_launch(void* const* d_in, const int* in_sizes, int n_in,
                              void* d_out, int out_size, void* d_ws, size_t ws_size,
                              hipStream_t stream) {
    const float* U    = (const float*)d_in[0];   // [16384,64]
    const float* B    = (const float*)d_in[1];   // [64,4096]
    const float* rsU  = (const float*)d_in[2];   // [16384,1]
    const float* rsB  = (const float*)d_in[3];   // [64,1]
    const float* cb   = (const float*)d_in[4];   // [2048,16]
    float* C = (float*)d_out;                    // [16384,4096]

    char* w = (char*)d_ws;                       // needs ~5.25 MB
    float* pbest = (float*)(w + OFF_PBEST);
    int*   pidx  = (int*)(w + OFF_PIDX);
    float* cb2   = (float*)(w + OFF_CB2);
    __hip_bfloat16* Uqh  = (__hip_bfloat16*)(w + OFF_UQH);
    __hip_bfloat16* BqTh = (__hip_bfloat16*)(w + OFF_BQTH);

    cb2_kernel<<<KCB / 256, 256, 0, stream>>>(cb, cb2);
    pq_partial<<<(NSUB * NQ) / 256, 256, 0, stream>>>(U, B, rsU, rsB, cb, cb2,
                                                      pbest, pidx);
    pq_combine<<<NSUB / 256, 256, 0, stream>>>(cb, rsU, rsB, pbest, pidx,
                                               Uqh, BqTh);
    mm_mfma<<<dim3(64, 256), 256, 0, stream>>>(Uqh, BqTh, C);
}

// Round 2
// 427.408 us; speedup vs baseline: 3.5028x; 3.5028x over previous
//
#include <hip/hip_runtime.h>
#include <hip/hip_bf16.h>
#include <float.h>

// Problem constants (PQHotShared): U[16384,64], B[64,4096], codebook[2048,16]
static constexpr int KCB    = 2048;   // codebook entries
static constexpr int DSUB   = 16;    // subvector length
static constexpr int NSUB_U = 65536; // 16384*64/16
static constexpr int NSUB_B = 16384; // 64*4096/16
static constexpr int NSUB   = NSUB_U + NSUB_B; // 81920
static constexpr int NQ     = 4;     // codebook split for load balance
static constexpr int CPQ    = KCB / NQ; // 512

typedef __attribute__((ext_vector_type(8))) short s16x8;   // 8 x bf16 (4 VGPRs)
typedef __attribute__((ext_vector_type(4))) float f32x4;

// ---------------- ws layout (bytes) ----------------
static constexpr size_t OFF_PBEST = 0;
static constexpr size_t OFF_PIDX  = 1310720;
static constexpr size_t OFF_CB2   = 2621440;
static constexpr size_t OFF_UQH   = 2629632;
static constexpr size_t OFF_BQTH  = 4726784;

// ||cb_c||^2 with numpy pairwise order for n=16:
//   r[j] = a[j] + a[j+8];  res = ((r0+r1)+(r2+r3)) + ((r4+r5)+(r6+r7))
__global__ __launch_bounds__(256) void cb2_kernel(const float* __restrict__ cb,
                                                  float* __restrict__ cb2) {
    int c = blockIdx.x * 256 + threadIdx.x;   // grid covers exactly 2048
    const float* p = cb + (size_t)c * DSUB;
    float a[16];
#pragma unroll
    for (int j = 0; j < 16; j++) { float v = p[j]; a[j] = fmaf(v, v, 0.0f); }
    float r[8];
#pragma unroll
    for (int j = 0; j < 8; j++) r[j] = a[j] + a[j + 8];
    float res = ((r[0] + r[1]) + (r[2] + r[3])) + ((r[4] + r[5]) + (r[6] + r[7]));
    cb2[c] = res;
}

// One WAVE per (64-subvector chunk, codebook quarter). The codeword index is
// wave-uniform (readfirstlane) -> codebook/cb2 loads are scalar s_load through
// the SMEM pipe; the VALU runs pure fmaf chains (1 SGPR operand each).
// 5120 wave-tasks over 1024 SIMDs -> 5 waves/SIMD, balanced.
// Accumulation order / tie semantics identical to the round-1 passing version:
// sequential fmaf chain k=0..15 per codeword, e = c2 - 2*d via single fma
// (2*d exact, so c2-(2*d) has one rounding either way), strict '<' ascending
// scan (first-index-wins), quarters merged in order by pq_combine.
__global__ __launch_bounds__(256) void pq_partial(
    const float* __restrict__ U, const float* __restrict__ B,
    const float* __restrict__ rsU, const float* __restrict__ rsB,
    const float* __restrict__ cb, const float* __restrict__ cb2,
    float* __restrict__ pbest, int* __restrict__ pidx)
{
    int wave = __builtin_amdgcn_readfirstlane(threadIdx.x >> 6); // SGPR
    int lane = threadIdx.x & 63;
    int wid  = blockIdx.x * 4 + wave;     // 0..5119, wave-uniform
    int q    = wid & 3;                   // codebook quarter, uniform
    int sub  = (wid >> 2) * 64 + lane;    // subvector, per-lane

    const float* wp;
    float rs;
    if (sub < NSUB_U) {                // U subvector (whole wave uniform branch)
        wp = U + (size_t)sub * DSUB;
        rs = rsU[sub >> 2];
    } else {
        int s = sub - NSUB_U;
        wp = B + (size_t)s * DSUB;
        rs = rsB[s >> 8];
    }
    float g[16];
#pragma unroll
    for (int k = 0; k < 16; k++) g[k] = wp[k] / rs;   // IEEE div, matches np

    const int c0 = q * CPQ;               // uniform
    const float* cbp = cb + (size_t)c0 * DSUB;   // uniform base -> s_load
    const float* c2p = cb2 + c0;

    float best = FLT_MAX;
    int bi = 0;
#pragma unroll 1
    for (int c = 0; c < CPQ; c += 4) {   // 4 independent chains for ILP
        const float* p0 = cbp + (size_t)c * DSUB;   // uniform address
        float d0 = 0.f, d1 = 0.f, d2 = 0.f, d3 = 0.f;
#pragma unroll
        for (int k = 0; k < 16; k++) {
            d0 = fmaf(g[k], p0[k],      d0);
            d1 = fmaf(g[k], p0[16 + k], d1);
            d2 = fmaf(g[k], p0[32 + k], d2);
            d3 = fmaf(g[k], p0[48 + k], d3);
        }
        float e0 = fmaf(-2.0f, d0, c2p[c + 0]);
        float e1 = fmaf(-2.0f, d1, c2p[c + 1]);
        float e2 = fmaf(-2.0f, d2, c2p[c + 2]);
        float e3 = fmaf(-2.0f, d3, c2p[c + 3]);
        if (e0 < best) { best = e0; bi = c + 0; }
        if (e1 < best) { best = e1; bi = c + 1; }
        if (e2 < best) { best = e2; bi = c + 2; }
        if (e3 < best) { best = e3; bi = c + 3; }
    }
    pbest[(size_t)sub * 4 + q] = best;
    pidx[(size_t)sub * 4 + q]  = c0 + bi;
}

// Merge the 4 quarter-results (in order -> first-index tie semantics),
// dequantize, cast to bf16. Uq stored [16384][64] row-major; Bq stored
// transposed as BqT [4096 cols][64 k] for MFMA B-fragment loads.
__global__ __launch_bounds__(256) void pq_combine(
    const float* __restrict__ cb,
    const float* __restrict__ rsU, const float* __restrict__ rsB,
    const float* __restrict__ pbest, const int* __restrict__ pidx,
    __hip_bfloat16* __restrict__ Uqh, __hip_bfloat16* __restrict__ BqTh)
{
    int sub = blockIdx.x * 256 + threadIdx.x;   // < 81920 exactly
    float4 b4 = ((const float4*)pbest)[sub];
    int4   i4 = ((const int4*)pidx)[sub];
    float best = b4.x; int bi = i4.x;
    if (b4.y < best) { best = b4.y; bi = i4.y; }
    if (b4.z < best) { best = b4.z; bi = i4.z; }
    if (b4.w < best) { best = b4.w; bi = i4.w; }

    const float* cp = cb + (size_t)bi * DSUB;
    if (sub < NSUB_U) {
        float rs = rsU[sub >> 2];
        union { __hip_bfloat16 h[16]; uint4 u4[2]; } u;
#pragma unroll
        for (int j = 0; j < 16; j++) u.h[j] = __float2bfloat16(cp[j] * rs);
        uint4* dst = (uint4*)(Uqh + (size_t)sub * DSUB);
        dst[0] = u.u4[0];
        dst[1] = u.u4[1];
    } else {
        int s = sub - NSUB_U;
        int kk = s >> 8;                 // B row (k index), 0..63
        int dbase = (s & 255) * DSUB;    // output column base
        float rs = rsB[kk];
#pragma unroll
        for (int j = 0; j < 16; j++)
            BqTh[(size_t)(dbase + j) * 64 + kk] = __float2bfloat16(cp[j] * rs);
    }
}

// C[16384,4096] = Uq @ Bq via mfma_f32_16x16x32_bf16, K=64 (2 mfma per tile).
// One wave computes a 16-row x 64-col strip (4 n-tiles). HBM-write-bound.
__global__ __launch_bounds__(256) void mm_mfma(
    const __hip_bfloat16* __restrict__ A,   // [16384][64]
    const __hip_bfloat16* __restrict__ BT,  // [4096][64]
    float* __restrict__ C)
{
    int wave = threadIdx.x >> 6;
    int lane = threadIdx.x & 63;
    int rb  = ((blockIdx.y << 2) | wave) << 4;   // row base, 16 rows
    int cb0 = blockIdx.x << 6;                   // col base, 64 cols
    int mrow = lane & 15;
    int quad = lane >> 4;
    int kidx = quad * 8;

    const s16x8* ap = (const s16x8*)(A + (size_t)(rb + mrow) * 64 + kidx);
    s16x8 a0 = ap[0];     // k in [kidx, kidx+8)
    s16x8 a1 = ap[4];     // k in [32+kidx, 32+kidx+8)

    f32x4 acc[4] = {};
#pragma unroll
    for (int nt = 0; nt < 4; nt++) {
        const s16x8* bp =
            (const s16x8*)(BT + (size_t)(cb0 + nt * 16 + mrow) * 64 + kidx);
        s16x8 b0 = bp[0];
        s16x8 b1 = bp[4];
        acc[nt] = __builtin_amdgcn_mfma_f32_16x16x32_bf16(a0, b0, acc[nt], 0, 0, 0);
        acc[nt] = __builtin_amdgcn_mfma_f32_16x16x32_bf16(a1, b1, acc[nt], 0, 0, 0);
    }

#pragma unroll
    for (int nt = 0; nt < 4; nt++) {
#pragma unroll
        for (int i = 0; i < 4; i++) {
            C[(size_t)(rb + quad * 4 + i) * 4096 + (cb0 + nt * 16 + mrow)] =
                acc[nt][i];
        }
    }
}

extern "C" void kernel_launch(void* const* d_in, const int* in_sizes, int n_in,
                              void* d_out, int out_size, void* d_ws, size_t ws_size,
                              hipStream_t stream) {
    const float* U    = (const float*)d_in[0];   // [16384,64]
    const float* B    = (const float*)d_in[1];   // [64,4096]
    const float* rsU  = (const float*)d_in[2];   // [16384,1]
    const float* rsB  = (const float*)d_in[3];   // [64,1]
    const float* cb   = (const float*)d_in[4];   // [2048,16]
    float* C = (float*)d_out;                    // [16384,4096]

    char* w = (char*)d_ws;                       // needs ~5.25 MB
    float* pbest = (float*)(w + OFF_PBEST);
    int*   pidx  = (int*)(w + OFF_PIDX);
    float* cb2   = (float*)(w + OFF_CB2);
    __hip_bfloat16* Uqh  = (__hip_bfloat16*)(w + OFF_UQH);
    __hip_bfloat16* BqTh = (__hip_bfloat16*)(w + OFF_BQTH);

    cb2_kernel<<<KCB / 256, 256, 0, stream>>>(cb, cb2);
    pq_partial<<<(NSUB * NQ / 64) / 4, 256, 0, stream>>>(U, B, rsU, rsB, cb, cb2,
                                                         pbest, pidx);
    pq_combine<<<NSUB / 256, 256, 0, stream>>>(cb, rsU, rsB, pbest, pidx,
                                               Uqh, BqTh);
    mm_mfma<<<dim3(64, 256), 256, 0, stream>>>(Uqh, BqTh, C);
}